// Round 1
// baseline (555.262 us; speedup 1.0000x reference)
//
#include <hip/hip_runtime.h>
#include <cstdint>

#define B_    2
#define S_    2048
#define HID_  2048
#define H_    16
#define HKV_  4
#define D_    128
#define SCALE_ 0.08838834764831845f   // 1/sqrt(128)
#define LOG2E_ 1.4426950408889634f

typedef __bf16 bf16x8 __attribute__((ext_vector_type(8)));
typedef float  f32x4  __attribute__((ext_vector_type(4)));
using u16 = unsigned short;

static __device__ __forceinline__ u16 f2bf(float f) {
  union { float f; uint32_t u; } c; c.f = f;
  uint32_t u = c.u;
  return (u16)((u + 0x7FFFu + ((u >> 16) & 1u)) >> 16);  // RNE
}
static __device__ __forceinline__ float bf2f(u16 h) {
  union { uint32_t u; float f; } c; c.u = ((uint32_t)h) << 16;
  return c.f;
}
static __device__ __forceinline__ void async16(const u16* g, u16* lds) {
  __builtin_amdgcn_global_load_lds((const __attribute__((address_space(1))) void*)g,
                                   (__attribute__((address_space(3))) void*)lds, 16, 0, 0);
}

// ---------------- cast x (f32 -> bf16), 4 elems/thread ----------------
__global__ void cast_f32_bf16(const float* __restrict__ in, u16* __restrict__ out, int n4) {
  int i = blockIdx.x * blockDim.x + threadIdx.x;
  if (i < n4) {
    float4 v = ((const float4*)in)[i];
    ushort4 o;
    o.x = f2bf(v.x); o.y = f2bf(v.y); o.z = f2bf(v.z); o.w = f2bf(v.w);
    ((ushort4*)out)[i] = o;
  }
}

// ---------------- transpose + cast: W (K x N) f32 -> Wt (N x K) bf16 ----------------
__global__ __launch_bounds__(256) void transpose_cast(const float* __restrict__ W,
                                                      u16* __restrict__ Wt, int K, int N) {
  __shared__ float tile[32][33];
  const int tx = threadIdx.x, ty = threadIdx.y;
  const int n0 = blockIdx.x * 32, k0 = blockIdx.y * 32;
#pragma unroll
  for (int j = 0; j < 32; j += 8)
    tile[ty + j][tx] = W[(size_t)(k0 + ty + j) * N + n0 + tx];
  __syncthreads();
#pragma unroll
  for (int j = 0; j < 32; j += 8)
    Wt[(size_t)(n0 + ty + j) * K + k0 + tx] = f2bf(tile[tx][ty + j]);
}

// ---------------- GEMM: C(MxN) f32 = A(MxK) bf16 * Bt(NxK)^T bf16 ----------------
// 128x128 tile, BK=64, 4 waves (2x2), 16x16x32 MFMA, global_load_lds + XOR swizzle.
__global__ __launch_bounds__(256) void gemm_bt_f32(const u16* __restrict__ A,
                                                   const u16* __restrict__ Bt,
                                                   float* __restrict__ C,
                                                   int M, int N, int K) {
  __shared__ __align__(16) u16 Ash[128 * 64];
  __shared__ __align__(16) u16 Bsh[128 * 64];
  const int tid = threadIdx.x;
  const int w = tid >> 6, l = tid & 63;
  const int bm = blockIdx.x * 128;
  const int bn = blockIdx.y * 128;
  const int wm = (w >> 1) * 64, wn = (w & 1) * 64;

  const f32x4 z4 = {0.f, 0.f, 0.f, 0.f};
  f32x4 acc[4][4];
#pragma unroll
  for (int i = 0; i < 4; ++i)
#pragma unroll
    for (int j = 0; j < 4; ++j) acc[i][j] = z4;

  const int srow = w * 8 + (l >> 3);  // + i*32
  const int schunk = l & 7;

  for (int k0 = 0; k0 < K; k0 += 64) {
#pragma unroll
    for (int i = 0; i < 4; ++i) {
      const int row = i * 32 + srow;
      const int ch = schunk ^ (row & 7);  // inverse-swizzled source, linear LDS dest
      async16(A + (size_t)(bm + row) * K + k0 + ch * 8, &Ash[(i * 4 + w) * 512]);
      async16(Bt + (size_t)(bn + row) * K + k0 + ch * 8, &Bsh[(i * 4 + w) * 512]);
    }
    asm volatile("s_waitcnt vmcnt(0)" ::: "memory");
    __syncthreads();
#pragma unroll
    for (int kc = 0; kc < 2; ++kc) {
      bf16x8 af[4], bfr[4];
#pragma unroll
      for (int mi = 0; mi < 4; ++mi) {
        const int r = wm + mi * 16 + (l & 15);
        const int c2 = (kc * 4 + (l >> 4)) ^ (r & 7);
        af[mi] = *(const bf16x8*)&Ash[r * 64 + c2 * 8];
      }
#pragma unroll
      for (int ni = 0; ni < 4; ++ni) {
        const int r = wn + ni * 16 + (l & 15);
        const int c2 = (kc * 4 + (l >> 4)) ^ (r & 7);
        bfr[ni] = *(const bf16x8*)&Bsh[r * 64 + c2 * 8];
      }
#pragma unroll
      for (int mi = 0; mi < 4; ++mi)
#pragma unroll
        for (int ni = 0; ni < 4; ++ni)
          acc[mi][ni] = __builtin_amdgcn_mfma_f32_16x16x32_bf16(af[mi], bfr[ni], acc[mi][ni], 0, 0, 0);
    }
    __syncthreads();
  }
#pragma unroll
  for (int mi = 0; mi < 4; ++mi) {
    const int r0 = bm + wm + mi * 16 + ((l >> 4) << 2);
#pragma unroll
    for (int ni = 0; ni < 4; ++ni) {
      const int c = bn + wn + ni * 16 + (l & 15);
#pragma unroll
      for (int j = 0; j < 4; ++j)
        C[(size_t)(r0 + j) * N + c] = acc[mi][ni][j];
    }
  }
}

// ---------------- RoPE + scatter into (b,h,s,d) bf16 buffers ----------------
__global__ void rope_scatter(const float* __restrict__ qkv,
                             const float* __restrict__ cosb, const float* __restrict__ sinb,
                             u16* __restrict__ Qr, u16* __restrict__ Kr, u16* __restrict__ Vr) {
  const int NQ = B_ * S_ * H_ * 64;
  const int NK = B_ * S_ * HKV_ * 64;
  const int NV = B_ * S_ * HKV_ * 128;
  const int idx = blockIdx.x * 256 + threadIdx.x;
  if (idx < NQ) {
    const int j = idx & 63, rest = idx >> 6;
    const int h = rest & 15, srow = rest >> 4;
    const int s = srow & (S_ - 1);
    const float* base = qkv + (size_t)srow * 3072 + h * 128;
    const float c = cosb[s * 128 + j], sn = sinb[s * 128 + j];
    const float a = base[j], b2 = base[j + 64];
    const size_t qo = (((size_t)(srow >> 11) * H_ + h) * S_ + s) * D_;
    Qr[qo + j]      = f2bf(a * c - b2 * sn);
    Qr[qo + j + 64] = f2bf(b2 * c + a * sn);
  } else if (idx < NQ + NK) {
    const int t = idx - NQ;
    const int j = t & 63, rest = t >> 6;
    const int kv = rest & 3, srow = rest >> 2;
    const int s = srow & (S_ - 1);
    const float* base = qkv + (size_t)srow * 3072 + 2048 + kv * 128;
    const float c = cosb[s * 128 + j], sn = sinb[s * 128 + j];
    const float a = base[j], b2 = base[j + 64];
    const size_t ko = (((size_t)(srow >> 11) * HKV_ + kv) * S_ + s) * D_;
    Kr[ko + j]      = f2bf(a * c - b2 * sn);
    Kr[ko + j + 64] = f2bf(b2 * c + a * sn);
  } else if (idx < NQ + NK + NV) {
    const int t = idx - NQ - NK;
    const int d = t & 127, rest = t >> 7;
    const int kv = rest & 3, srow = rest >> 2;
    const int s = srow & (S_ - 1);
    const size_t vo = (((size_t)(srow >> 11) * HKV_ + kv) * S_ + s) * D_;
    Vr[vo + d] = f2bf(qkv[(size_t)srow * 3072 + 2560 + kv * 128 + d]);
  }
}

// ---------------- causal GQA flash attention ----------------
// Block: 256 thr = 4 waves; each wave owns 16 q-rows (QBLK=64), KVBLK=64, D=128.
__global__ __launch_bounds__(256) void attn_kernel(const u16* __restrict__ Q,
                                                   const u16* __restrict__ Kc,
                                                   const u16* __restrict__ Vc,
                                                   u16* __restrict__ O) {
  const int qt = (int)gridDim.x - 1 - (int)blockIdx.x;  // longest blocks first
  const int bh = blockIdx.y;
  const int b = bh >> 4;
  const int kvh = (bh & 15) >> 2;   // N_REP = 4
  const int tid = threadIdx.x;
  const int w = tid >> 6, l = tid & 63;
  const int q0 = qt * 64;

  __shared__ __align__(16) u16 Ksh[64 * 128];   // row-major, swizzled slots
  __shared__ __align__(16) u16 Vsh[128 * 64];   // transposed [d][s], swizzled slots
  __shared__ __align__(16) u16 Psh[4][16 * 64]; // per-wave P

  bf16x8 qf[4];
  {
    const int r = q0 + w * 16 + (l & 15);
    const u16* qp = Q + ((size_t)bh * S_ + r) * D_ + (l >> 4) * 8;
#pragma unroll
    for (int kc = 0; kc < 4; ++kc) qf[kc] = *(const bf16x8*)(qp + kc * 32);
  }

  const f32x4 z4 = {0.f, 0.f, 0.f, 0.f};
  f32x4 oacc[8];
#pragma unroll
  for (int nb = 0; nb < 8; ++nb) oacc[nb] = z4;
  float m_i[4], l_i[4];
#pragma unroll
  for (int j = 0; j < 4; ++j) { m_i[j] = -1e30f; l_i[j] = 0.f; }

  const u16* Kbase = Kc + ((size_t)(b * HKV_ + kvh) * S_) * D_;
  const u16* Vbase = Vc + ((size_t)(b * HKV_ + kvh) * S_) * D_;
  const int rbase = q0 + w * 16 + ((l >> 4) << 2);

  for (int kv0 = 0; kv0 <= q0; kv0 += 64) {
    // stage K tile via global_load_lds (inverse-swizzled source)
#pragma unroll
    for (int i = 0; i < 4; ++i) {
      const int row = i * 16 + w * 4 + (l >> 4);
      const int ch = (l & 15) ^ (row & 7);
      async16(Kbase + (size_t)(kv0 + row) * D_ + ch * 8, &Ksh[(i * 4 + w) * 512]);
    }
    // stage V transposed via regs (8-wide global load, scattered ds_write_b16)
#pragma unroll
    for (int i = 0; i < 4; ++i) {
      const int row = i * 16 + (tid >> 4);
      const int cc = tid & 15;
      uint4 vd = *(const uint4*)(Vbase + (size_t)(kv0 + row) * D_ + cc * 8);
      const u16* vs = (const u16*)&vd;
#pragma unroll
      for (int j = 0; j < 8; ++j) {
        const int d = cc * 8 + j;
        const int slot = (row >> 3) ^ (d & 7);
        Vsh[d * 64 + slot * 8 + (row & 7)] = vs[j];
      }
    }
    asm volatile("s_waitcnt vmcnt(0)" ::: "memory");
    __syncthreads();

    // ---- QK^T : S(16x64) = Q(16x128) x K^T
    f32x4 sf[4];
#pragma unroll
    for (int nb = 0; nb < 4; ++nb) sf[nb] = z4;
#pragma unroll
    for (int kc = 0; kc < 4; ++kc) {
#pragma unroll
      for (int nb = 0; nb < 4; ++nb) {
        const int r = nb * 16 + (l & 15);
        const int c2 = (kc * 4 + (l >> 4)) ^ (r & 7);
        const bf16x8 kf = *(const bf16x8*)&Ksh[r * 128 + c2 * 8];
        sf[nb] = __builtin_amdgcn_mfma_f32_16x16x32_bf16(qf[kc], kf, sf[nb], 0, 0, 0);
      }
    }

    // ---- online softmax (rows live in 16-lane groups, 4 rows/lane as regs)
    float pv[4][4];
#pragma unroll
    for (int j = 0; j < 4; ++j) {
      float mx = -1e30f;
#pragma unroll
      for (int nb = 0; nb < 4; ++nb) {
        float sv = sf[nb][j] * SCALE_;
        const int col = kv0 + nb * 16 + (l & 15);
        sv = (col > rbase + j) ? -1e30f : sv;   // causal mask
        pv[j][nb] = sv;
        mx = fmaxf(mx, sv);
      }
#pragma unroll
      for (int st = 1; st < 16; st <<= 1) mx = fmaxf(mx, __shfl_xor(mx, st));
      const float mnew = fmaxf(m_i[j], mx);
      const float fsc = exp2f((m_i[j] - mnew) * LOG2E_);
      m_i[j] = mnew;
      float rs = 0.f;
#pragma unroll
      for (int nb = 0; nb < 4; ++nb) {
        const float p = exp2f((pv[j][nb] - mnew) * LOG2E_);
        pv[j][nb] = p;
        rs += p;
      }
#pragma unroll
      for (int st = 1; st < 16; st <<= 1) rs += __shfl_xor(rs, st);
      l_i[j] = l_i[j] * fsc + rs;
#pragma unroll
      for (int nb = 0; nb < 8; ++nb) oacc[nb][j] *= fsc;
    }

    // ---- P -> per-wave LDS (bf16, swizzled), then PV
    u16* Pw = &Psh[w][0];
#pragma unroll
    for (int j = 0; j < 4; ++j) {
      const int r = ((l >> 4) << 2) + j;
#pragma unroll
      for (int nb = 0; nb < 4; ++nb) {
        const int c = nb * 16 + (l & 15);
        const int slot = (c >> 3) ^ (r & 7);
        Pw[r * 64 + slot * 8 + (c & 7)] = f2bf(pv[j][nb]);
      }
    }
    asm volatile("s_waitcnt lgkmcnt(0)" ::: "memory");

#pragma unroll
    for (int kc = 0; kc < 2; ++kc) {
      const int rP = l & 15;
      const int c2 = (kc * 4 + (l >> 4)) ^ (rP & 7);
      const bf16x8 pf = *(const bf16x8*)&Pw[rP * 64 + c2 * 8];
      const int srowV = kc * 32 + (l >> 4) * 8;
#pragma unroll
      for (int nb = 0; nb < 8; ++nb) {
        const int d = nb * 16 + (l & 15);
        const int slot = (srowV >> 3) ^ (d & 7);
        const bf16x8 vf = *(const bf16x8*)&Vsh[d * 64 + slot * 8];
        oacc[nb] = __builtin_amdgcn_mfma_f32_16x16x32_bf16(pf, vf, oacc[nb], 0, 0, 0);
      }
    }
    __syncthreads();
  }

  // epilogue: normalize, write O as (b, s, h*128+d) bf16
#pragma unroll
  for (int j = 0; j < 4; ++j) {
    const float inv = 1.f / l_i[j];
    const int s = rbase + j;
    u16* op = O + ((size_t)(b * S_ + s)) * HID_ + (bh & 15) * D_ + (l & 15);
#pragma unroll
    for (int nb = 0; nb < 8; ++nb) op[nb * 16] = f2bf(oacc[nb][j] * inv);
  }
}

// ---------------- host launch ----------------
extern "C" void kernel_launch(void* const* d_in, const int* in_sizes, int n_in,
                              void* d_out, int out_size, void* d_ws, size_t ws_size,
                              hipStream_t stream) {
  const float* x    = (const float*)d_in[0];
  const float* cosb = (const float*)d_in[1];
  const float* sinb = (const float*)d_in[2];
  const float* Wq   = (const float*)d_in[3];
  const float* Wk   = (const float*)d_in[4];
  const float* Wv   = (const float*)d_in[5];
  const float* Wo   = (const float*)d_in[6];
  float* out = (float*)d_out;

  // workspace layout (bf16 except qkv f32); total ~130 MB
  u16*   xb  = (u16*)d_ws;                                 // 4096*2048
  u16*   Wt  = xb  + (size_t)4096 * 2048;                  // 3072*2048 (Wq|Wk|Wv transposed)
  u16*   Wot = Wt  + (size_t)3072 * 2048;                  // 2048*2048
  float* qkv = (float*)(Wot + (size_t)2048 * 2048);        // 4096*3072 f32
  u16*   Qr  = (u16*)(qkv + (size_t)4096 * 3072);          // (B,H,S,D)
  u16*   Kr  = Qr + (size_t)B_ * H_ * S_ * D_;             // (B,HKV,S,D)
  u16*   Vr  = Kr + (size_t)B_ * HKV_ * S_ * D_;
  u16*   Ob  = Vr + (size_t)B_ * HKV_ * S_ * D_;           // (B,S,HID)

  // 1. cast x -> bf16
  cast_f32_bf16<<<8192, 256, 0, stream>>>(x, xb, (B_ * S_ * HID_) / 4);

  // 2. transpose+cast weights: Wt rows = output cols
  dim3 tb(32, 8);
  transpose_cast<<<dim3(64, 64), tb, 0, stream>>>(Wq, Wt, 2048, 2048);
  transpose_cast<<<dim3(16, 64), tb, 0, stream>>>(Wk, Wt + (size_t)2048 * 2048, 2048, 512);
  transpose_cast<<<dim3(16, 64), tb, 0, stream>>>(Wv, Wt + (size_t)2560 * 2048, 2048, 512);
  transpose_cast<<<dim3(64, 64), tb, 0, stream>>>(Wo, Wot, 2048, 2048);

  // 3. fused QKV projection: qkv(4096x3072) = xb @ [Wq|Wk|Wv]
  gemm_bt_f32<<<dim3(32, 24), 256, 0, stream>>>(xb, Wt, qkv, 4096, 3072, 2048);

  // 4. RoPE + scatter to (b,h,s,d)
  rope_scatter<<<28672, 256, 0, stream>>>(qkv, cosb, sinb, Qr, Kr, Vr);

  // 5. causal GQA flash attention
  attn_kernel<<<dim3(32, 32), 256, 0, stream>>>(Qr, Kr, Vr, Ob);

  // 6. output projection: out(4096x2048) = Ob @ Wo
  gemm_bt_f32<<<dim3(32, 16), 256, 0, stream>>>(Ob, Wot, out, 4096, 2048, 2048);
}

// Round 3
// 256.007 us; speedup vs baseline: 2.1689x; 2.1689x over previous
//
#include <hip/hip_runtime.h>
#include <cstdint>

#define B_    2
#define S_    2048
#define HID_  2048
#define H_    16
#define HKV_  4
#define D_    128
#define SCALE_ 0.08838834764831845f   // 1/sqrt(128)
#define LOG2E_ 1.4426950408889634f
#define K1_   (SCALE_ * LOG2E_)

typedef __bf16 bf16x8 __attribute__((ext_vector_type(8)));
typedef float  f32x4  __attribute__((ext_vector_type(4)));
typedef int    intx2  __attribute__((ext_vector_type(2)));
using u16 = unsigned short;

static __device__ __forceinline__ u16 f2bf(float f) {
  union { float f; uint32_t u; } c; c.f = f;
  uint32_t u = c.u;
  return (u16)((u + 0x7FFFu + ((u >> 16) & 1u)) >> 16);  // RNE
}
static __device__ __forceinline__ void async16(const u16* g, u16* lds) {
  __builtin_amdgcn_global_load_lds((const __attribute__((address_space(1))) void*)g,
                                   (__attribute__((address_space(3))) void*)lds, 16, 0, 0);
}

// ---------------- cast x (f32 -> bf16), 4 elems/thread ----------------
__global__ void cast_f32_bf16(const float* __restrict__ in, u16* __restrict__ out, int n4) {
  int i = blockIdx.x * blockDim.x + threadIdx.x;
  if (i < n4) {
    float4 v = ((const float4*)in)[i];
    ushort4 o;
    o.x = f2bf(v.x); o.y = f2bf(v.y); o.z = f2bf(v.z); o.w = f2bf(v.w);
    ((ushort4*)out)[i] = o;
  }
}

// ---------------- transpose + cast: W (K x N) f32 -> Wt (N x K) bf16 ----------------
__global__ __launch_bounds__(256) void transpose_cast(const float* __restrict__ W,
                                                      u16* __restrict__ Wt, int K, int N) {
  __shared__ float tile[32][33];
  const int tx = threadIdx.x, ty = threadIdx.y;
  const int n0 = blockIdx.x * 32, k0 = blockIdx.y * 32;
#pragma unroll
  for (int j = 0; j < 32; j += 8)
    tile[ty + j][tx] = W[(size_t)(k0 + ty + j) * N + n0 + tx];
  __syncthreads();
#pragma unroll
  for (int j = 0; j < 32; j += 8)
    Wt[(size_t)(n0 + ty + j) * K + k0 + tx] = f2bf(tile[tx][ty + j]);
}

// ---------------- V transpose: qkv f32 (b,s)[2560+kv*128+d] -> Vt bf16 [mat][d][s] ----------------
__global__ __launch_bounds__(256) void v_transpose(const float* __restrict__ qkv,
                                                   u16* __restrict__ Vt) {
  __shared__ float tile[32][33];
  const int tx = threadIdx.x, ty = threadIdx.y;
  const int mat = blockIdx.z;            // b*HKV + kv
  const int b = mat >> 2, kv = mat & 3;
  const int d0 = blockIdx.x * 32, s0 = blockIdx.y * 32;
#pragma unroll
  for (int j = 0; j < 32; j += 8)
    tile[ty + j][tx] = qkv[(size_t)(b * S_ + s0 + ty + j) * 3072 + 2560 + kv * 128 + d0 + tx];
  __syncthreads();
#pragma unroll
  for (int j = 0; j < 32; j += 8)
    Vt[((size_t)mat * D_ + d0 + ty + j) * S_ + s0 + tx] = f2bf(tile[tx][ty + j]);
}

// ---------------- GEMM: C(MxN) f32 = A(MxK) bf16 * Bt(NxK)^T bf16 ----------------
__global__ __launch_bounds__(256) void gemm_bt_f32(const u16* __restrict__ A,
                                                   const u16* __restrict__ Bt,
                                                   float* __restrict__ C,
                                                   int M, int N, int K) {
  __shared__ __align__(16) u16 Ash[128 * 64];
  __shared__ __align__(16) u16 Bsh[128 * 64];
  const int tid = threadIdx.x;
  const int w = tid >> 6, l = tid & 63;
  const int bm = blockIdx.x * 128;
  const int bn = blockIdx.y * 128;
  const int wm = (w >> 1) * 64, wn = (w & 1) * 64;

  const f32x4 z4 = {0.f, 0.f, 0.f, 0.f};
  f32x4 acc[4][4];
#pragma unroll
  for (int i = 0; i < 4; ++i)
#pragma unroll
    for (int j = 0; j < 4; ++j) acc[i][j] = z4;

  const int srow = w * 8 + (l >> 3);
  const int schunk = l & 7;

  for (int k0 = 0; k0 < K; k0 += 64) {
#pragma unroll
    for (int i = 0; i < 4; ++i) {
      const int row = i * 32 + srow;
      const int ch = schunk ^ (row & 7);
      async16(A + (size_t)(bm + row) * K + k0 + ch * 8, &Ash[(i * 4 + w) * 512]);
      async16(Bt + (size_t)(bn + row) * K + k0 + ch * 8, &Bsh[(i * 4 + w) * 512]);
    }
    asm volatile("s_waitcnt vmcnt(0)" ::: "memory");
    __syncthreads();
#pragma unroll
    for (int kc = 0; kc < 2; ++kc) {
      bf16x8 af[4], bfr[4];
#pragma unroll
      for (int mi = 0; mi < 4; ++mi) {
        const int r = wm + mi * 16 + (l & 15);
        const int c2 = (kc * 4 + (l >> 4)) ^ (r & 7);
        af[mi] = *(const bf16x8*)&Ash[r * 64 + c2 * 8];
      }
#pragma unroll
      for (int ni = 0; ni < 4; ++ni) {
        const int r = wn + ni * 16 + (l & 15);
        const int c2 = (kc * 4 + (l >> 4)) ^ (r & 7);
        bfr[ni] = *(const bf16x8*)&Bsh[r * 64 + c2 * 8];
      }
#pragma unroll
      for (int mi = 0; mi < 4; ++mi)
#pragma unroll
        for (int ni = 0; ni < 4; ++ni)
          acc[mi][ni] = __builtin_amdgcn_mfma_f32_16x16x32_bf16(af[mi], bfr[ni], acc[mi][ni], 0, 0, 0);
    }
    __syncthreads();
  }
#pragma unroll
  for (int mi = 0; mi < 4; ++mi) {
    const int r0 = bm + wm + mi * 16 + ((l >> 4) << 2);
#pragma unroll
    for (int ni = 0; ni < 4; ++ni) {
      const int c = bn + wn + ni * 16 + (l & 15);
#pragma unroll
      for (int j = 0; j < 4; ++j)
        C[(size_t)(r0 + j) * N + c] = acc[mi][ni][j];
    }
  }
}

// ---------------- RoPE + scatter Q,K into (b,h,s,d) bf16 buffers ----------------
__global__ void rope_scatter(const float* __restrict__ qkv,
                             const float* __restrict__ cosb, const float* __restrict__ sinb,
                             u16* __restrict__ Qr, u16* __restrict__ Kr) {
  const int NQ = B_ * S_ * H_ * 64;
  const int NK = B_ * S_ * HKV_ * 64;
  const int idx = blockIdx.x * 256 + threadIdx.x;
  if (idx < NQ) {
    const int j = idx & 63, rest = idx >> 6;
    const int h = rest & 15, srow = rest >> 4;
    const int s = srow & (S_ - 1);
    const float* base = qkv + (size_t)srow * 3072 + h * 128;
    const float c = cosb[s * 128 + j], sn = sinb[s * 128 + j];
    const float a = base[j], b2 = base[j + 64];
    const size_t qo = (((size_t)(srow >> 11) * H_ + h) * S_ + s) * D_;
    Qr[qo + j]      = f2bf(a * c - b2 * sn);
    Qr[qo + j + 64] = f2bf(b2 * c + a * sn);
  } else if (idx < NQ + NK) {
    const int t = idx - NQ;
    const int j = t & 63, rest = t >> 6;
    const int kv = rest & 3, srow = rest >> 2;
    const int s = srow & (S_ - 1);
    const float* base = qkv + (size_t)srow * 3072 + 2048 + kv * 128;
    const float c = cosb[s * 128 + j], sn = sinb[s * 128 + j];
    const float a = base[j], b2 = base[j + 64];
    const size_t ko = (((size_t)(srow >> 11) * HKV_ + kv) * S_ + s) * D_;
    Kr[ko + j]      = f2bf(a * c - b2 * sn);
    Kr[ko + j + 64] = f2bf(b2 * c + a * sn);
  }
}

// ---------------- causal GQA flash attention v3 ----------------
// 4 waves x 32 q-rows (QBLK=128), KVBLK=64. Swapped QK^T (lane owns q-col),
// in-register softmax, PV B-frags from transposed V via plain ds_read_b64
// with 16B-granule XOR swizzle. Double-buffered global_load_lds staging.
__global__ __launch_bounds__(256, 2) void attn_kernel(const u16* __restrict__ Q,
                                                      const u16* __restrict__ Kc,
                                                      const u16* __restrict__ Vt,
                                                      u16* __restrict__ O) {
  const int bid = blockIdx.x;
  const int bh  = bid & 31;
  const int qt  = 15 - (bid >> 5);      // longest blocks dispatched first
  const int b   = bh >> 4;
  const int kvh = (bh & 15) >> 2;       // N_REP = 4
  const int tid = threadIdx.x;
  const int w = tid >> 6, l = tid & 63;
  const int g = l >> 4, c = l & 15;
  const int q0 = qt * 128;

  __shared__ __align__(16) u16 KshF[2 * 64 * 128];   // [kv][d], chunk^=(kv&7) swizzle
  __shared__ __align__(16) u16 VshF[2 * 128 * 64];   // [d][kv], 16B-granule^=(d&7) swizzle

  const u16* Kbase = Kc + ((size_t)(b * HKV_ + kvh) * S_) * D_;   // [s][d]
  const u16* Vbase = Vt + ((size_t)(b * HKV_ + kvh) * D_) * S_;   // [d][s]

  // Q fragments (B-operand): lane holds Q[q0+w*32+qg*16+c][kc*32+g*8+j]
  bf16x8 qf[2][4];
#pragma unroll
  for (int qg = 0; qg < 2; ++qg) {
    const u16* qp = Q + ((size_t)bh * S_ + q0 + w * 32 + qg * 16 + c) * D_ + g * 8;
#pragma unroll
    for (int kc = 0; kc < 4; ++kc) qf[qg][kc] = *(const bf16x8*)(qp + kc * 32);
  }

  // staging source offsets (per-lane, per-issue i); LDS dest linear at lane*16B
  int srcK[4], srcV[4];
#pragma unroll
  for (int i = 0; i < 4; ++i) {
    const int rK = i * 16 + w * 4 + g;                  // K row this lane stages
    srcK[i] = rK * 128 + (c ^ (rK & 7)) * 8;
    const int dV = i * 32 + w * 8 + (l >> 3);           // V d-row this lane stages
    srcV[i] = dV * S_ + ((l & 7) ^ (dV & 7)) * 8;       // pre-permuted granule
  }

  const f32x4 z4 = {0.f, 0.f, 0.f, 0.f};
  f32x4 oacc[2][8];
#pragma unroll
  for (int qg = 0; qg < 2; ++qg)
#pragma unroll
    for (int nb = 0; nb < 8; ++nb) oacc[qg][nb] = z4;
  float m_i[2] = {-1e30f, -1e30f}, l_i[2] = {0.f, 0.f};

  auto stage = [&](int buf, int kv0) {
#pragma unroll
    for (int i = 0; i < 4; ++i) {
      async16(Kbase + (size_t)kv0 * 128 + srcK[i], &KshF[buf * 8192 + i * 2048 + w * 512]);
      async16(Vbase + kv0 + srcV[i],               &VshF[buf * 8192 + i * 2048 + w * 512]);
    }
  };

  // per-lane PV read base (bytes within VshF tile):
  // element = d*64 + (granule^(d&7))*8 + half*4 ; d = nb*16+c, granule = kc2*4+(g>>1), half = g&1
  const uint32_t voff = (uint32_t)(c * 128 + (((g >> 1) ^ (c & 7)) << 4) + ((g & 1) << 3));

  const int nt = (q0 + 128) >> 6;
  stage(0, 0);
  __syncthreads();

  for (int t = 0; t < nt; ++t) {
    const int cur = t & 1;
    const int kv0 = t << 6;
    if (t + 1 < nt) stage(cur ^ 1, (t + 1) << 6);

    const u16*  Kb = &KshF[cur * 8192];
    const char* Vb = (const char*)&VshF[cur * 8192];

    // ---- QK^T swapped: sf[qg][nb][jj] = S[kv=kv0+nb*16+g*4+jj][q=q0+w*32+qg*16+c]
    f32x4 sf[2][4];
#pragma unroll
    for (int qg = 0; qg < 2; ++qg)
#pragma unroll
      for (int nb = 0; nb < 4; ++nb) sf[qg][nb] = z4;

    __builtin_amdgcn_s_setprio(1);
#pragma unroll
    for (int kc = 0; kc < 4; ++kc) {
#pragma unroll
      for (int nb = 0; nb < 4; ++nb) {
        const int r = nb * 16 + c;
        const int s2 = (kc * 4 + g) ^ (c & 7);          // r&7 == c&7
        const bf16x8 kf = *(const bf16x8*)&Kb[r * 128 + s2 * 8];
        sf[0][nb] = __builtin_amdgcn_mfma_f32_16x16x32_bf16(kf, qf[0][kc], sf[0][nb], 0, 0, 0);
        sf[1][nb] = __builtin_amdgcn_mfma_f32_16x16x32_bf16(kf, qf[1][kc], sf[1][nb], 0, 0, 0);
      }
    }
    __builtin_amdgcn_s_setprio(0);

    // ---- online softmax (lane owns q-col = q0+w*32+qg*16+c; reduce over g via shfl)
#pragma unroll
    for (int qg = 0; qg < 2; ++qg) {
      const int qcol = q0 + w * 32 + qg * 16 + c;
      const bool doMask = (kv0 + 63 > q0 + w * 32 + qg * 16);
      float mx = -3e38f;
#pragma unroll
      for (int nb = 0; nb < 4; ++nb)
#pragma unroll
        for (int jj = 0; jj < 4; ++jj) {
          float sv = sf[qg][nb][jj];
          if (doMask) {
            const int kk = kv0 + nb * 16 + g * 4 + jj;
            sv = (kk > qcol) ? -3e38f : sv;
            sf[qg][nb][jj] = sv;
          }
          mx = fmaxf(mx, sv);
        }
      mx = fmaxf(mx, __shfl_xor(mx, 16));
      mx = fmaxf(mx, __shfl_xor(mx, 32));
      const float mnew = fmaxf(m_i[qg], mx);
      const float fsc = exp2f((m_i[qg] - mnew) * K1_);
      m_i[qg] = mnew;
      const float mk = mnew * K1_;
      float rs = 0.f;
#pragma unroll
      for (int nb = 0; nb < 4; ++nb)
#pragma unroll
        for (int jj = 0; jj < 4; ++jj) {
          const float p = exp2f(fmaf(sf[qg][nb][jj], K1_, -mk));
          sf[qg][nb][jj] = p;
          rs += p;
        }
      rs += __shfl_xor(rs, 16);
      rs += __shfl_xor(rs, 32);
      l_i[qg] = l_i[qg] * fsc + rs;
      // rescale O (C-layout rows: q_local16 = g*4+j)
      float fq[4];
#pragma unroll
      for (int j = 0; j < 4; ++j) fq[j] = __shfl(fsc, g * 4 + j);
#pragma unroll
      for (int nb = 0; nb < 8; ++nb)
#pragma unroll
        for (int j = 0; j < 4; ++j) oacc[qg][nb][j] *= fq[j];
    }

    // ---- pack P into PV A-frags: kappa=g*8+e -> kv = kc2*32 + (e>>2)*16 + g*4 + (e&3)
    bf16x8 paq0, paq1, pbq0, pbq1;
#pragma unroll
    for (int jj = 0; jj < 4; ++jj) {
      paq0[jj] = (__bf16)sf[0][0][jj]; paq0[4 + jj] = (__bf16)sf[0][1][jj];
      pbq0[jj] = (__bf16)sf[0][2][jj]; pbq0[4 + jj] = (__bf16)sf[0][3][jj];
      paq1[jj] = (__bf16)sf[1][0][jj]; paq1[4 + jj] = (__bf16)sf[1][1][jj];
      pbq1[jj] = (__bf16)sf[1][2][jj]; pbq1[4 + jj] = (__bf16)sf[1][3][jj];
    }

    // ---- PV: B-frag = V[kv(kappa)][d=nb*16+c] via two ds_read_b64 (XOR-swizzled)
    __builtin_amdgcn_s_setprio(1);
#pragma unroll
    for (int kc2 = 0; kc2 < 2; ++kc2) {
      const bf16x8 pa0 = kc2 ? pbq0 : paq0;
      const bf16x8 pa1 = kc2 ? pbq1 : paq1;
      const uint32_t vk = voff ^ (uint32_t)(kc2 << 6);
#pragma unroll
      for (int nb = 0; nb < 8; ++nb) {
        union { intx2 h[2]; bf16x8 v; } u_;
        u_.h[0] = *(const intx2*)(Vb + (vk + nb * 2048));          // kv low 16 (j=0..3)
        u_.h[1] = *(const intx2*)(Vb + ((vk ^ 32u) + nb * 2048));  // kv high 16 (j=4..7)
        oacc[0][nb] = __builtin_amdgcn_mfma_f32_16x16x32_bf16(pa0, u_.v, oacc[0][nb], 0, 0, 0);
        oacc[1][nb] = __builtin_amdgcn_mfma_f32_16x16x32_bf16(pa1, u_.v, oacc[1][nb], 0, 0, 0);
      }
    }
    __builtin_amdgcn_s_setprio(0);

    __syncthreads();   // drains vmcnt (next tile staged) + all reads of cur done
  }

  // epilogue: normalize, write O as (b, s, h*128+d) bf16
#pragma unroll
  for (int qg = 0; qg < 2; ++qg)
#pragma unroll
    for (int j = 0; j < 4; ++j) {
      const float li = __shfl(l_i[qg], g * 4 + j);
      const float inv = 1.f / li;
      const int srow = q0 + w * 32 + qg * 16 + g * 4 + j;
      u16* op = O + ((size_t)(b * S_ + srow)) * HID_ + (bh & 15) * D_ + c;
#pragma unroll
      for (int nb = 0; nb < 8; ++nb) op[nb * 16] = f2bf(oacc[qg][nb][j] * inv);
    }
}

// ---------------- host launch ----------------
extern "C" void kernel_launch(void* const* d_in, const int* in_sizes, int n_in,
                              void* d_out, int out_size, void* d_ws, size_t ws_size,
                              hipStream_t stream) {
  const float* x    = (const float*)d_in[0];
  const float* cosb = (const float*)d_in[1];
  const float* sinb = (const float*)d_in[2];
  const float* Wq   = (const float*)d_in[3];
  const float* Wk   = (const float*)d_in[4];
  const float* Wv   = (const float*)d_in[5];
  const float* Wo   = (const float*)d_in[6];
  float* out = (float*)d_out;

  u16*   xb  = (u16*)d_ws;                                 // 4096*2048
  u16*   Wt  = xb  + (size_t)4096 * 2048;                  // 3072*2048
  u16*   Wot = Wt  + (size_t)3072 * 2048;                  // 2048*2048
  float* qkv = (float*)(Wot + (size_t)2048 * 2048);        // 4096*3072 f32
  u16*   Qr  = (u16*)(qkv + (size_t)4096 * 3072);          // (B,H,S,D)
  u16*   Kr  = Qr + (size_t)B_ * H_ * S_ * D_;             // (B,HKV,S,D)
  u16*   Vtb = Kr + (size_t)B_ * HKV_ * S_ * D_;           // (B,HKV,D,S) transposed
  u16*   Ob  = Vtb + (size_t)B_ * HKV_ * S_ * D_;          // (B,S,HID)

  cast_f32_bf16<<<8192, 256, 0, stream>>>(x, xb, (B_ * S_ * HID_) / 4);

  dim3 tb(32, 8);
  transpose_cast<<<dim3(64, 64), tb, 0, stream>>>(Wq, Wt, 2048, 2048);
  transpose_cast<<<dim3(16, 64), tb, 0, stream>>>(Wk, Wt + (size_t)2048 * 2048, 2048, 512);
  transpose_cast<<<dim3(16, 64), tb, 0, stream>>>(Wv, Wt + (size_t)2560 * 2048, 2048, 512);
  transpose_cast<<<dim3(64, 64), tb, 0, stream>>>(Wo, Wot, 2048, 2048);

  gemm_bt_f32<<<dim3(32, 24), 256, 0, stream>>>(xb, Wt, qkv, 4096, 3072, 2048);

  rope_scatter<<<20480, 256, 0, stream>>>(qkv, cosb, sinb, Qr, Kr);
  v_transpose<<<dim3(4, 64, 8), tb, 0, stream>>>(qkv, Vtb);

  attn_kernel<<<dim3(512), 256, 0, stream>>>(Qr, Kr, Vtb, Ob);

  gemm_bt_f32<<<dim3(32, 16), 256, 0, stream>>>(Ob, Wot, out, 4096, 2048, 2048);
}

// Round 4
// 245.680 us; speedup vs baseline: 2.2601x; 1.0420x over previous
//
#include <hip/hip_runtime.h>
#include <cstdint>

#define B_    2
#define S_    2048
#define HID_  2048
#define H_    16
#define HKV_  4
#define D_    128
#define SCALE_ 0.08838834764831845f   // 1/sqrt(128)
#define LOG2E_ 1.4426950408889634f
#define K1_   (SCALE_ * LOG2E_)
#define THRS_ 62.75f                  // ~8 / K1_ : defer-max threshold (P <= 2^8)

typedef __bf16 bf16x8 __attribute__((ext_vector_type(8)));
typedef float  f32x4  __attribute__((ext_vector_type(4)));
typedef int    intx2  __attribute__((ext_vector_type(2)));
using u16 = unsigned short;

static __device__ __forceinline__ u16 f2bf(float f) {
  union { float f; uint32_t u; } c; c.f = f;
  uint32_t u = c.u;
  return (u16)((u + 0x7FFFu + ((u >> 16) & 1u)) >> 16);  // RNE
}
static __device__ __forceinline__ float bf2f(u16 h) {
  union { uint32_t u; float f; } c; c.u = ((uint32_t)h) << 16;
  return c.f;
}
static __device__ __forceinline__ void async16(const u16* g, u16* lds) {
  __builtin_amdgcn_global_load_lds((const __attribute__((address_space(1))) void*)g,
                                   (__attribute__((address_space(3))) void*)lds, 16, 0, 0);
}

// ---------------- cast x (f32 -> bf16), 4 elems/thread ----------------
__global__ void cast_f32_bf16(const float* __restrict__ in, u16* __restrict__ out, int n4) {
  int i = blockIdx.x * blockDim.x + threadIdx.x;
  if (i < n4) {
    float4 v = ((const float4*)in)[i];
    ushort4 o;
    o.x = f2bf(v.x); o.y = f2bf(v.y); o.z = f2bf(v.z); o.w = f2bf(v.w);
    ((ushort4*)out)[i] = o;
  }
}

// ---------------- transpose + cast: W (K x N) f32 -> Wt (N x K) bf16 ----------------
__global__ __launch_bounds__(256) void transpose_cast(const float* __restrict__ W,
                                                      u16* __restrict__ Wt, int K, int N) {
  __shared__ float tile[32][33];
  const int tx = threadIdx.x, ty = threadIdx.y;
  const int n0 = blockIdx.x * 32, k0 = blockIdx.y * 32;
#pragma unroll
  for (int j = 0; j < 32; j += 8)
    tile[ty + j][tx] = W[(size_t)(k0 + ty + j) * N + n0 + tx];
  __syncthreads();
#pragma unroll
  for (int j = 0; j < 32; j += 8)
    Wt[(size_t)(n0 + ty + j) * K + k0 + tx] = f2bf(tile[tx][ty + j]);
}

// ---------------- V transpose: qkv bf16 (b,s)[2560+kv*128+d] -> Vt bf16 [mat][d][s] ----------------
__global__ __launch_bounds__(256) void v_transpose(const u16* __restrict__ qkv,
                                                   u16* __restrict__ Vt) {
  __shared__ u16 tile[32][34];
  const int tx = threadIdx.x, ty = threadIdx.y;
  const int mat = blockIdx.z;            // b*HKV + kv
  const int b = mat >> 2, kv = mat & 3;
  const int d0 = blockIdx.x * 32, s0 = blockIdx.y * 32;
#pragma unroll
  for (int j = 0; j < 32; j += 8)
    tile[ty + j][tx] = qkv[(size_t)(b * S_ + s0 + ty + j) * 3072 + 2560 + kv * 128 + d0 + tx];
  __syncthreads();
#pragma unroll
  for (int j = 0; j < 32; j += 8)
    Vt[((size_t)mat * D_ + d0 + ty + j) * S_ + s0 + tx] = tile[tx][ty + j];
}

// ---------------- GEMM: C(MxN) = A(MxK) bf16 * Bt(NxK)^T bf16; XCD-chunked 1-D grid ----------------
template<int BF16OUT>
__global__ __launch_bounds__(256) void gemm_bt(const u16* __restrict__ A,
                                               const u16* __restrict__ Bt,
                                               void* __restrict__ Cv,
                                               int M, int N, int K, int gx) {
  // bijective XCD-chunked swizzle (m204 form): consecutive wg within an XCD chunk
  const int nwg = (int)gridDim.x;
  const int bid = (int)blockIdx.x;
  const int qq = nwg >> 3, rr = nwg & 7;
  const int xcd = bid & 7, pos = bid >> 3;
  const int wg = ((xcd < rr) ? xcd * (qq + 1) : rr * (qq + 1) + (xcd - rr) * qq) + pos;
  const int bm = (wg % gx) * 128;
  const int bn = (wg / gx) * 128;

  __shared__ __align__(16) u16 Ash[128 * 64];
  __shared__ __align__(16) u16 Bsh[128 * 64];
  const int tid = threadIdx.x;
  const int w = tid >> 6, l = tid & 63;
  const int wm = (w >> 1) * 64, wn = (w & 1) * 64;

  const f32x4 z4 = {0.f, 0.f, 0.f, 0.f};
  f32x4 acc[4][4];
#pragma unroll
  for (int i = 0; i < 4; ++i)
#pragma unroll
    for (int j = 0; j < 4; ++j) acc[i][j] = z4;

  const int srow = w * 8 + (l >> 3);
  const int schunk = l & 7;

  for (int k0 = 0; k0 < K; k0 += 64) {
#pragma unroll
    for (int i = 0; i < 4; ++i) {
      const int row = i * 32 + srow;
      const int ch = schunk ^ (row & 7);
      async16(A + (size_t)(bm + row) * K + k0 + ch * 8, &Ash[(i * 4 + w) * 512]);
      async16(Bt + (size_t)(bn + row) * K + k0 + ch * 8, &Bsh[(i * 4 + w) * 512]);
    }
    asm volatile("s_waitcnt vmcnt(0)" ::: "memory");
    __syncthreads();
#pragma unroll
    for (int kc = 0; kc < 2; ++kc) {
      bf16x8 af[4], bfr[4];
#pragma unroll
      for (int mi = 0; mi < 4; ++mi) {
        const int r = wm + mi * 16 + (l & 15);
        const int c2 = (kc * 4 + (l >> 4)) ^ (r & 7);
        af[mi] = *(const bf16x8*)&Ash[r * 64 + c2 * 8];
      }
#pragma unroll
      for (int ni = 0; ni < 4; ++ni) {
        const int r = wn + ni * 16 + (l & 15);
        const int c2 = (kc * 4 + (l >> 4)) ^ (r & 7);
        bfr[ni] = *(const bf16x8*)&Bsh[r * 64 + c2 * 8];
      }
#pragma unroll
      for (int mi = 0; mi < 4; ++mi)
#pragma unroll
        for (int ni = 0; ni < 4; ++ni)
          acc[mi][ni] = __builtin_amdgcn_mfma_f32_16x16x32_bf16(af[mi], bfr[ni], acc[mi][ni], 0, 0, 0);
    }
    __syncthreads();
  }
#pragma unroll
  for (int mi = 0; mi < 4; ++mi) {
    const int r0 = bm + wm + mi * 16 + ((l >> 4) << 2);
#pragma unroll
    for (int ni = 0; ni < 4; ++ni) {
      const int c = bn + wn + ni * 16 + (l & 15);
#pragma unroll
      for (int j = 0; j < 4; ++j) {
        if (BF16OUT) ((u16*)Cv)[(size_t)(r0 + j) * N + c] = f2bf(acc[mi][ni][j]);
        else         ((float*)Cv)[(size_t)(r0 + j) * N + c] = acc[mi][ni][j];
      }
    }
  }
}

// ---------------- RoPE + scatter Q,K (bf16 qkv in) ----------------
__global__ void rope_scatter(const u16* __restrict__ qkv,
                             const float* __restrict__ cosb, const float* __restrict__ sinb,
                             u16* __restrict__ Qr, u16* __restrict__ Kr) {
  const int NQ = B_ * S_ * H_ * 64;
  const int NK = B_ * S_ * HKV_ * 64;
  const int idx = blockIdx.x * 256 + threadIdx.x;
  if (idx < NQ) {
    const int j = idx & 63, rest = idx >> 6;
    const int h = rest & 15, srow = rest >> 4;
    const int s = srow & (S_ - 1);
    const u16* base = qkv + (size_t)srow * 3072 + h * 128;
    const float c = cosb[s * 128 + j], sn = sinb[s * 128 + j];
    const float a = bf2f(base[j]), b2 = bf2f(base[j + 64]);
    const size_t qo = (((size_t)(srow >> 11) * H_ + h) * S_ + s) * D_;
    Qr[qo + j]      = f2bf(a * c - b2 * sn);
    Qr[qo + j + 64] = f2bf(b2 * c + a * sn);
  } else if (idx < NQ + NK) {
    const int t = idx - NQ;
    const int j = t & 63, rest = t >> 6;
    const int kv = rest & 3, srow = rest >> 2;
    const int s = srow & (S_ - 1);
    const u16* base = qkv + (size_t)srow * 3072 + 2048 + kv * 128;
    const float c = cosb[s * 128 + j], sn = sinb[s * 128 + j];
    const float a = bf2f(base[j]), b2 = bf2f(base[j + 64]);
    const size_t ko = (((size_t)(srow >> 11) * HKV_ + kv) * S_ + s) * D_;
    Kr[ko + j]      = f2bf(a * c - b2 * sn);
    Kr[ko + j + 64] = f2bf(b2 * c + a * sn);
  }
}

// ---------------- causal GQA flash attention v4 ----------------
// v3 + defer-max rescale skip + wave-uniform masked-tile skip.
__global__ __launch_bounds__(256, 2) void attn_kernel(const u16* __restrict__ Q,
                                                      const u16* __restrict__ Kc,
                                                      const u16* __restrict__ Vt,
                                                      u16* __restrict__ O) {
  const int bid = blockIdx.x;
  const int bh  = bid & 31;
  const int qt  = 15 - (bid >> 5);      // longest blocks dispatched first
  const int b   = bh >> 4;
  const int kvh = (bh & 15) >> 2;       // N_REP = 4
  const int tid = threadIdx.x;
  const int w = tid >> 6, l = tid & 63;
  const int g = l >> 4, c = l & 15;
  const int q0 = qt * 128;

  __shared__ __align__(16) u16 KshF[2 * 64 * 128];   // [kv][d], chunk^=(kv&7) swizzle
  __shared__ __align__(16) u16 VshF[2 * 128 * 64];   // [d][kv], 16B-granule^=(d&7) swizzle

  const u16* Kbase = Kc + ((size_t)(b * HKV_ + kvh) * S_) * D_;   // [s][d]
  const u16* Vbase = Vt + ((size_t)(b * HKV_ + kvh) * D_) * S_;   // [d][s]

  // Q fragments (B-operand): lane holds Q[q0+w*32+qg*16+c][kc*32+g*8+j]
  bf16x8 qf[2][4];
#pragma unroll
  for (int qg = 0; qg < 2; ++qg) {
    const u16* qp = Q + ((size_t)bh * S_ + q0 + w * 32 + qg * 16 + c) * D_ + g * 8;
#pragma unroll
    for (int kc = 0; kc < 4; ++kc) qf[qg][kc] = *(const bf16x8*)(qp + kc * 32);
  }

  // staging source offsets (per-lane, per-issue i); LDS dest linear at lane*16B
  int srcK[4], srcV[4];
#pragma unroll
  for (int i = 0; i < 4; ++i) {
    const int rK = i * 16 + w * 4 + g;                  // K row this lane stages
    srcK[i] = rK * 128 + (c ^ (rK & 7)) * 8;
    const int dV = i * 32 + w * 8 + (l >> 3);           // V d-row this lane stages
    srcV[i] = dV * S_ + ((l & 7) ^ (dV & 7)) * 8;       // pre-permuted granule
  }

  const f32x4 z4 = {0.f, 0.f, 0.f, 0.f};
  f32x4 oacc[2][8];
#pragma unroll
  for (int qg = 0; qg < 2; ++qg)
#pragma unroll
    for (int nb = 0; nb < 8; ++nb) oacc[qg][nb] = z4;
  float m_i[2] = {-1e30f, -1e30f}, l_i[2] = {0.f, 0.f};

  auto stage = [&](int buf, int kv0) {
#pragma unroll
    for (int i = 0; i < 4; ++i) {
      async16(Kbase + (size_t)kv0 * 128 + srcK[i], &KshF[buf * 8192 + i * 2048 + w * 512]);
      async16(Vbase + kv0 + srcV[i],               &VshF[buf * 8192 + i * 2048 + w * 512]);
    }
  };

  // per-lane PV read base (bytes within VshF tile):
  // element = d*64 + (granule^(d&7))*8 + half*4 ; d = nb*16+c, granule = kc2*4+(g>>1), half = g&1
  const uint32_t voff = (uint32_t)(c * 128 + (((g >> 1) ^ (c & 7)) << 4) + ((g & 1) << 3));

  const int nt = (q0 + 128) >> 6;
  stage(0, 0);
  __syncthreads();

  for (int t = 0; t < nt; ++t) {
    const int cur = t & 1;
    const int kv0 = t << 6;
    if (t + 1 < nt) stage(cur ^ 1, (t + 1) << 6);

    // wave-uniform skip: this wave's 32 q-rows all above-masked for this tile
    if (kv0 <= q0 + w * 32 + 31) {
      const u16*  Kb = &KshF[cur * 8192];
      const char* Vb = (const char*)&VshF[cur * 8192];

      // ---- QK^T swapped: sf[qg][nb][jj] = S[kv=kv0+nb*16+g*4+jj][q=q0+w*32+qg*16+c]
      f32x4 sf[2][4];
#pragma unroll
      for (int qg = 0; qg < 2; ++qg)
#pragma unroll
        for (int nb = 0; nb < 4; ++nb) sf[qg][nb] = z4;

      __builtin_amdgcn_s_setprio(1);
#pragma unroll
      for (int kc = 0; kc < 4; ++kc) {
#pragma unroll
        for (int nb = 0; nb < 4; ++nb) {
          const int r = nb * 16 + c;
          const int s2 = (kc * 4 + g) ^ (c & 7);          // r&7 == c&7
          const bf16x8 kf = *(const bf16x8*)&Kb[r * 128 + s2 * 8];
          sf[0][nb] = __builtin_amdgcn_mfma_f32_16x16x32_bf16(kf, qf[0][kc], sf[0][nb], 0, 0, 0);
          sf[1][nb] = __builtin_amdgcn_mfma_f32_16x16x32_bf16(kf, qf[1][kc], sf[1][nb], 0, 0, 0);
        }
      }
      __builtin_amdgcn_s_setprio(0);

      // ---- online softmax (lane owns q-col); defer-max skips rescale
#pragma unroll
      for (int qg = 0; qg < 2; ++qg) {
        const int qcol = q0 + w * 32 + qg * 16 + c;
        const bool doMask = (kv0 + 63 > q0 + w * 32 + qg * 16);
        float mx = -3e38f;
#pragma unroll
        for (int nb = 0; nb < 4; ++nb)
#pragma unroll
          for (int jj = 0; jj < 4; ++jj) {
            float sv = sf[qg][nb][jj];
            if (doMask) {
              const int kk = kv0 + nb * 16 + g * 4 + jj;
              sv = (kk > qcol) ? -3e38f : sv;
              sf[qg][nb][jj] = sv;
            }
            mx = fmaxf(mx, sv);
          }
        mx = fmaxf(mx, __shfl_xor(mx, 16));
        mx = fmaxf(mx, __shfl_xor(mx, 32));

        if (__all(mx <= m_i[qg] + THRS_)) {
          // defer: keep old max, no O/l rescale (P bounded by 2^8)
          const float mk = m_i[qg] * K1_;
          float rs = 0.f;
#pragma unroll
          for (int nb = 0; nb < 4; ++nb)
#pragma unroll
            for (int jj = 0; jj < 4; ++jj) {
              const float p = exp2f(fmaf(sf[qg][nb][jj], K1_, -mk));
              sf[qg][nb][jj] = p;
              rs += p;
            }
          rs += __shfl_xor(rs, 16);
          rs += __shfl_xor(rs, 32);
          l_i[qg] += rs;
        } else {
          const float mnew = fmaxf(m_i[qg], mx);
          const float fsc = exp2f((m_i[qg] - mnew) * K1_);
          m_i[qg] = mnew;
          const float mk = mnew * K1_;
          float rs = 0.f;
#pragma unroll
          for (int nb = 0; nb < 4; ++nb)
#pragma unroll
            for (int jj = 0; jj < 4; ++jj) {
              const float p = exp2f(fmaf(sf[qg][nb][jj], K1_, -mk));
              sf[qg][nb][jj] = p;
              rs += p;
            }
          rs += __shfl_xor(rs, 16);
          rs += __shfl_xor(rs, 32);
          l_i[qg] = l_i[qg] * fsc + rs;
          float fq[4];
#pragma unroll
          for (int j = 0; j < 4; ++j) fq[j] = __shfl(fsc, g * 4 + j);
#pragma unroll
          for (int nb = 0; nb < 8; ++nb)
#pragma unroll
            for (int j = 0; j < 4; ++j) oacc[qg][nb][j] *= fq[j];
        }
      }

      // ---- pack P into PV A-frags: kappa=g*8+e -> kv = kc2*32 + (e>>2)*16 + g*4 + (e&3)
      bf16x8 paq0, paq1, pbq0, pbq1;
#pragma unroll
      for (int jj = 0; jj < 4; ++jj) {
        paq0[jj] = (__bf16)sf[0][0][jj]; paq0[4 + jj] = (__bf16)sf[0][1][jj];
        pbq0[jj] = (__bf16)sf[0][2][jj]; pbq0[4 + jj] = (__bf16)sf[0][3][jj];
        paq1[jj] = (__bf16)sf[1][0][jj]; paq1[4 + jj] = (__bf16)sf[1][1][jj];
        pbq1[jj] = (__bf16)sf[1][2][jj]; pbq1[4 + jj] = (__bf16)sf[1][3][jj];
      }

      // ---- PV: B-frag = V[kv(kappa)][d=nb*16+c] via two ds_read_b64 (XOR-swizzled)
      __builtin_amdgcn_s_setprio(1);
#pragma unroll
      for (int kc2 = 0; kc2 < 2; ++kc2) {
        const bf16x8 pa0 = kc2 ? pbq0 : paq0;
        const bf16x8 pa1 = kc2 ? pbq1 : paq1;
        const uint32_t vk = voff ^ (uint32_t)(kc2 << 6);
#pragma unroll
        for (int nb = 0; nb < 8; ++nb) {
          union { intx2 h[2]; bf16x8 v; } u_;
          u_.h[0] = *(const intx2*)(Vb + (vk + nb * 2048));          // kv low 16 (j=0..3)
          u_.h[1] = *(const intx2*)(Vb + ((vk ^ 32u) + nb * 2048));  // kv high 16 (j=4..7)
          oacc[0][nb] = __builtin_amdgcn_mfma_f32_16x16x32_bf16(pa0, u_.v, oacc[0][nb], 0, 0, 0);
          oacc[1][nb] = __builtin_amdgcn_mfma_f32_16x16x32_bf16(pa1, u_.v, oacc[1][nb], 0, 0, 0);
        }
      }
      __builtin_amdgcn_s_setprio(0);
    }

    __syncthreads();   // drains vmcnt (next tile staged) + all reads of cur done
  }

  // epilogue: normalize, write O as (b, s, h*128+d) bf16
#pragma unroll
  for (int qg = 0; qg < 2; ++qg)
#pragma unroll
    for (int j = 0; j < 4; ++j) {
      const float li = __shfl(l_i[qg], g * 4 + j);
      const float inv = 1.f / li;
      const int srow = q0 + w * 32 + qg * 16 + g * 4 + j;
      u16* op = O + ((size_t)(b * S_ + srow)) * HID_ + (bh & 15) * D_ + c;
#pragma unroll
      for (int nb = 0; nb < 8; ++nb) op[nb * 16] = f2bf(oacc[qg][nb][j] * inv);
    }
}

// ---------------- host launch ----------------
extern "C" void kernel_launch(void* const* d_in, const int* in_sizes, int n_in,
                              void* d_out, int out_size, void* d_ws, size_t ws_size,
                              hipStream_t stream) {
  const float* x    = (const float*)d_in[0];
  const float* cosb = (const float*)d_in[1];
  const float* sinb = (const float*)d_in[2];
  const float* Wq   = (const float*)d_in[3];
  const float* Wk   = (const float*)d_in[4];
  const float* Wv   = (const float*)d_in[5];
  const float* Wo   = (const float*)d_in[6];
  float* out = (float*)d_out;

  u16*   xb   = (u16*)d_ws;                                // 4096*2048
  u16*   Wt   = xb  + (size_t)4096 * 2048;                 // 3072*2048
  u16*   Wot  = Wt  + (size_t)3072 * 2048;                 // 2048*2048
  u16*   qkv  = Wot + (size_t)2048 * 2048;                 // 4096*3072 bf16
  u16*   Qr   = qkv + (size_t)4096 * 3072;                 // (B,H,S,D)
  u16*   Kr   = Qr  + (size_t)B_ * H_ * S_ * D_;           // (B,HKV,S,D)
  u16*   Vtb  = Kr  + (size_t)B_ * HKV_ * S_ * D_;         // (B,HKV,D,S) transposed
  u16*   Ob   = Vtb + (size_t)B_ * HKV_ * S_ * D_;         // (B,S,HID)

  cast_f32_bf16<<<8192, 256, 0, stream>>>(x, xb, (B_ * S_ * HID_) / 4);

  dim3 tb(32, 8);
  transpose_cast<<<dim3(64, 64), tb, 0, stream>>>(Wq, Wt, 2048, 2048);
  transpose_cast<<<dim3(16, 64), tb, 0, stream>>>(Wk, Wt + (size_t)2048 * 2048, 2048, 512);
  transpose_cast<<<dim3(16, 64), tb, 0, stream>>>(Wv, Wt + (size_t)2560 * 2048, 2048, 512);
  transpose_cast<<<dim3(64, 64), tb, 0, stream>>>(Wo, Wot, 2048, 2048);

  // QKV projection (bf16 out), 1-D grid with XCD-chunked swizzle; gx = M/128 = 32
  gemm_bt<1><<<dim3(768), 256, 0, stream>>>(xb, Wt, qkv, 4096, 3072, 2048, 32);

  rope_scatter<<<20480, 256, 0, stream>>>(qkv, cosb, sinb, Qr, Kr);
  v_transpose<<<dim3(4, 64, 8), tb, 0, stream>>>(qkv, Vtb);

  attn_kernel<<<dim3(512), 256, 0, stream>>>(Qr, Kr, Vtb, Ob);

  // output projection (f32 out)
  gemm_bt<0><<<dim3(512), 256, 0, stream>>>(Ob, Wot, out, 4096, 2048, 2048, 32);
}

// Round 5
// 232.239 us; speedup vs baseline: 2.3909x; 1.0579x over previous
//
#include <hip/hip_runtime.h>
#include <cstdint>

#define B_    2
#define S_    2048
#define HID_  2048
#define H_    16
#define HKV_  4
#define D_    128
#define SCALE_ 0.08838834764831845f   // 1/sqrt(128)
#define LOG2E_ 1.4426950408889634f
#define K1_   (SCALE_ * LOG2E_)
#define THRS_ 62.75f                  // ~8 / K1_ : defer-max threshold (P <= 2^8)

typedef __bf16 bf16x8 __attribute__((ext_vector_type(8)));
typedef float  f32x4  __attribute__((ext_vector_type(4)));
typedef int    intx2  __attribute__((ext_vector_type(2)));
using u16 = unsigned short;

static __device__ __forceinline__ u16 f2bf(float f) {
  union { float f; uint32_t u; } c; c.f = f;
  uint32_t u = c.u;
  return (u16)((u + 0x7FFFu + ((u >> 16) & 1u)) >> 16);  // RNE
}
static __device__ __forceinline__ float bf2f(u16 h) {
  union { uint32_t u; float f; } c; c.u = ((uint32_t)h) << 16;
  return c.f;
}
static __device__ __forceinline__ void async16(const u16* g, u16* lds) {
  __builtin_amdgcn_global_load_lds((const __attribute__((address_space(1))) void*)g,
                                   (__attribute__((address_space(3))) void*)lds, 16, 0, 0);
}

// ---------------- cast x (f32 -> bf16), 4 elems/thread ----------------
__global__ void cast_f32_bf16(const float* __restrict__ in, u16* __restrict__ out, int n4) {
  int i = blockIdx.x * blockDim.x + threadIdx.x;
  if (i < n4) {
    float4 v = ((const float4*)in)[i];
    ushort4 o;
    o.x = f2bf(v.x); o.y = f2bf(v.y); o.z = f2bf(v.z); o.w = f2bf(v.w);
    ((ushort4*)out)[i] = o;
  }
}

// ---------------- fused transpose+cast of all 4 weights (1 launch) ----------------
// tiles: Wq 64x64 [0,4096) ; Wk 16x64 [4096,5120) ; Wv 16x64 [5120,6144) ; Wo 64x64 [6144,10240)
__global__ __launch_bounds__(256) void transpose_cast_all(const float* __restrict__ Wq,
                                                          const float* __restrict__ Wk,
                                                          const float* __restrict__ Wv,
                                                          const float* __restrict__ Wo,
                                                          u16* __restrict__ Wt,
                                                          u16* __restrict__ Wot) {
  __shared__ float tile[32][33];
  const int tx = threadIdx.x, ty = threadIdx.y;
  const int t = blockIdx.x;
  const float* W; u16* Dst; int N, lt;
  if (t < 4096)      { W = Wq; Dst = Wt;                        N = 2048; lt = t; }
  else if (t < 5120) { W = Wk; Dst = Wt + (size_t)2048 * 2048;  N = 512;  lt = t - 4096; }
  else if (t < 6144) { W = Wv; Dst = Wt + (size_t)2560 * 2048;  N = 512;  lt = t - 5120; }
  else               { W = Wo; Dst = Wot;                       N = 2048; lt = t - 6144; }
  const int tn = N >> 5;
  const int n0 = (lt % tn) * 32, k0 = (lt / tn) * 32;
#pragma unroll
  for (int j = 0; j < 32; j += 8)
    tile[ty + j][tx] = W[(size_t)(k0 + ty + j) * N + n0 + tx];
  __syncthreads();
#pragma unroll
  for (int j = 0; j < 32; j += 8)
    Dst[(size_t)(n0 + ty + j) * 2048 + k0 + tx] = f2bf(tile[tx][ty + j]);
}

// ---------------- V transpose: qkv bf16 (b,s)[2560+kv*128+d] -> Vt bf16 [mat][d][s] ----------------
__global__ __launch_bounds__(256) void v_transpose(const u16* __restrict__ qkv,
                                                   u16* __restrict__ Vt) {
  __shared__ u16 tile[32][34];
  const int tx = threadIdx.x, ty = threadIdx.y;
  const int mat = blockIdx.z;            // b*HKV + kv
  const int b = mat >> 2, kv = mat & 3;
  const int d0 = blockIdx.x * 32, s0 = blockIdx.y * 32;
#pragma unroll
  for (int j = 0; j < 32; j += 8)
    tile[ty + j][tx] = qkv[(size_t)(b * S_ + s0 + ty + j) * 3072 + 2560 + kv * 128 + d0 + tx];
  __syncthreads();
#pragma unroll
  for (int j = 0; j < 32; j += 8)
    Vt[((size_t)mat * D_ + d0 + ty + j) * S_ + s0 + tx] = tile[tx][ty + j];
}

// ---------------- GEMM: C(MxN) = A(MxK) bf16 * Bt(NxK)^T bf16; XCD-chunked 1-D grid ----------------
template<int BF16OUT>
__global__ __launch_bounds__(256, 4) void gemm_bt(const u16* __restrict__ A,
                                                  const u16* __restrict__ Bt,
                                                  void* __restrict__ Cv,
                                                  int M, int N, int K, int gx) {
  // bijective XCD-chunked swizzle (m204 form)
  const int nwg = (int)gridDim.x;
  const int bid = (int)blockIdx.x;
  const int qq = nwg >> 3, rr = nwg & 7;
  const int xcd = bid & 7, pos = bid >> 3;
  const int wg = ((xcd < rr) ? xcd * (qq + 1) : rr * (qq + 1) + (xcd - rr) * qq) + pos;
  const int bm = (wg % gx) * 128;
  const int bn = (wg / gx) * 128;

  __shared__ __align__(16) u16 Ash[128 * 64];
  __shared__ __align__(16) u16 Bsh[128 * 64];
  const int tid = threadIdx.x;
  const int w = tid >> 6, l = tid & 63;
  const int wm = (w >> 1) * 64, wn = (w & 1) * 64;

  const f32x4 z4 = {0.f, 0.f, 0.f, 0.f};
  f32x4 acc[4][4];
#pragma unroll
  for (int i = 0; i < 4; ++i)
#pragma unroll
    for (int j = 0; j < 4; ++j) acc[i][j] = z4;

  const int srow = w * 8 + (l >> 3);
  const int schunk = l & 7;

  for (int k0 = 0; k0 < K; k0 += 64) {
#pragma unroll
    for (int i = 0; i < 4; ++i) {
      const int row = i * 32 + srow;
      const int ch = schunk ^ (row & 7);
      async16(A + (size_t)(bm + row) * K + k0 + ch * 8, &Ash[(i * 4 + w) * 512]);
      async16(Bt + (size_t)(bn + row) * K + k0 + ch * 8, &Bsh[(i * 4 + w) * 512]);
    }
    asm volatile("s_waitcnt vmcnt(0)" ::: "memory");
    __syncthreads();
#pragma unroll
    for (int kc = 0; kc < 2; ++kc) {
      bf16x8 af[4], bfr[4];
#pragma unroll
      for (int mi = 0; mi < 4; ++mi) {
        const int r = wm + mi * 16 + (l & 15);
        const int c2 = (kc * 4 + (l >> 4)) ^ (r & 7);
        af[mi] = *(const bf16x8*)&Ash[r * 64 + c2 * 8];
      }
#pragma unroll
      for (int ni = 0; ni < 4; ++ni) {
        const int r = wn + ni * 16 + (l & 15);
        const int c2 = (kc * 4 + (l >> 4)) ^ (r & 7);
        bfr[ni] = *(const bf16x8*)&Bsh[r * 64 + c2 * 8];
      }
#pragma unroll
      for (int mi = 0; mi < 4; ++mi)
#pragma unroll
        for (int ni = 0; ni < 4; ++ni)
          acc[mi][ni] = __builtin_amdgcn_mfma_f32_16x16x32_bf16(af[mi], bfr[ni], acc[mi][ni], 0, 0, 0);
    }
    __syncthreads();
  }
#pragma unroll
  for (int mi = 0; mi < 4; ++mi) {
    const int r0 = bm + wm + mi * 16 + ((l >> 4) << 2);
#pragma unroll
    for (int ni = 0; ni < 4; ++ni) {
      const int c = bn + wn + ni * 16 + (l & 15);
#pragma unroll
      for (int j = 0; j < 4; ++j) {
        if (BF16OUT) ((u16*)Cv)[(size_t)(r0 + j) * N + c] = f2bf(acc[mi][ni][j]);
        else         ((float*)Cv)[(size_t)(r0 + j) * N + c] = acc[mi][ni][j];
      }
    }
  }
}

// ---------------- RoPE + scatter Q,K (bf16 qkv in) ----------------
__global__ void rope_scatter(const u16* __restrict__ qkv,
                             const float* __restrict__ cosb, const float* __restrict__ sinb,
                             u16* __restrict__ Qr, u16* __restrict__ Kr) {
  const int NQ = B_ * S_ * H_ * 64;
  const int NK = B_ * S_ * HKV_ * 64;
  const int idx = blockIdx.x * 256 + threadIdx.x;
  if (idx < NQ) {
    const int j = idx & 63, rest = idx >> 6;
    const int h = rest & 15, srow = rest >> 4;
    const int s = srow & (S_ - 1);
    const u16* base = qkv + (size_t)srow * 3072 + h * 128;
    const float c = cosb[s * 128 + j], sn = sinb[s * 128 + j];
    const float a = bf2f(base[j]), b2 = bf2f(base[j + 64]);
    const size_t qo = (((size_t)(srow >> 11) * H_ + h) * S_ + s) * D_;
    Qr[qo + j]      = f2bf(a * c - b2 * sn);
    Qr[qo + j + 64] = f2bf(b2 * c + a * sn);
  } else if (idx < NQ + NK) {
    const int t = idx - NQ;
    const int j = t & 63, rest = t >> 6;
    const int kv = rest & 3, srow = rest >> 2;
    const int s = srow & (S_ - 1);
    const u16* base = qkv + (size_t)srow * 3072 + 2048 + kv * 128;
    const float c = cosb[s * 128 + j], sn = sinb[s * 128 + j];
    const float a = bf2f(base[j]), b2 = bf2f(base[j + 64]);
    const size_t ko = (((size_t)(srow >> 11) * HKV_ + kv) * S_ + s) * D_;
    Kr[ko + j]      = f2bf(a * c - b2 * sn);
    Kr[ko + j + 64] = f2bf(b2 * c + a * sn);
  }
}

// ---------------- causal GQA flash attention v5 ----------------
// v4 + complementary-pair dispatch: block i and block i+256 share a CU (same XCD
// residue, same bh); their q-tiles are qt=15-(i>>5) and qt=(i>>5) -> per-CU work
// uniform at 34 kv-tiles.
__global__ __launch_bounds__(256, 2) void attn_kernel(const u16* __restrict__ Q,
                                                      const u16* __restrict__ Kc,
                                                      const u16* __restrict__ Vt,
                                                      u16* __restrict__ O) {
  const int bid = blockIdx.x;
  const int bh  = bid & 31;
  const int qt  = (bid < 256) ? (15 - ((bid >> 5) & 7)) : ((bid >> 5) & 7);
  const int b   = bh >> 4;
  const int kvh = (bh & 15) >> 2;       // N_REP = 4
  const int tid = threadIdx.x;
  const int w = tid >> 6, l = tid & 63;
  const int g = l >> 4, c = l & 15;
  const int q0 = qt * 128;

  __shared__ __align__(16) u16 KshF[2 * 64 * 128];   // [kv][d], chunk^=(kv&7) swizzle
  __shared__ __align__(16) u16 VshF[2 * 128 * 64];   // [d][kv], 16B-granule^=(d&7) swizzle

  const u16* Kbase = Kc + ((size_t)(b * HKV_ + kvh) * S_) * D_;   // [s][d]
  const u16* Vbase = Vt + ((size_t)(b * HKV_ + kvh) * D_) * S_;   // [d][s]

  // Q fragments (B-operand): lane holds Q[q0+w*32+qg*16+c][kc*32+g*8+j]
  bf16x8 qf[2][4];
#pragma unroll
  for (int qg = 0; qg < 2; ++qg) {
    const u16* qp = Q + ((size_t)bh * S_ + q0 + w * 32 + qg * 16 + c) * D_ + g * 8;
#pragma unroll
    for (int kc = 0; kc < 4; ++kc) qf[qg][kc] = *(const bf16x8*)(qp + kc * 32);
  }

  // staging source offsets (per-lane, per-issue i); LDS dest linear at lane*16B
  int srcK[4], srcV[4];
#pragma unroll
  for (int i = 0; i < 4; ++i) {
    const int rK = i * 16 + w * 4 + g;                  // K row this lane stages
    srcK[i] = rK * 128 + (c ^ (rK & 7)) * 8;
    const int dV = i * 32 + w * 8 + (l >> 3);           // V d-row this lane stages
    srcV[i] = dV * S_ + ((l & 7) ^ (dV & 7)) * 8;       // pre-permuted granule
  }

  const f32x4 z4 = {0.f, 0.f, 0.f, 0.f};
  f32x4 oacc[2][8];
#pragma unroll
  for (int qg = 0; qg < 2; ++qg)
#pragma unroll
    for (int nb = 0; nb < 8; ++nb) oacc[qg][nb] = z4;
  float m_i[2] = {-1e30f, -1e30f}, l_i[2] = {0.f, 0.f};

  auto stage = [&](int buf, int kv0) {
#pragma unroll
    for (int i = 0; i < 4; ++i) {
      async16(Kbase + (size_t)kv0 * 128 + srcK[i], &KshF[buf * 8192 + i * 2048 + w * 512]);
      async16(Vbase + kv0 + srcV[i],               &VshF[buf * 8192 + i * 2048 + w * 512]);
    }
  };

  // per-lane PV read base (bytes within VshF tile):
  // element = d*64 + (granule^(d&7))*8 + half*4 ; d = nb*16+c, granule = kc2*4+(g>>1), half = g&1
  const uint32_t voff = (uint32_t)(c * 128 + (((g >> 1) ^ (c & 7)) << 4) + ((g & 1) << 3));

  const int nt = (q0 + 128) >> 6;
  stage(0, 0);
  __syncthreads();

  for (int t = 0; t < nt; ++t) {
    const int cur = t & 1;
    const int kv0 = t << 6;
    if (t + 1 < nt) stage(cur ^ 1, (t + 1) << 6);

    // wave-uniform skip: this wave's 32 q-rows all above-masked for this tile
    if (kv0 <= q0 + w * 32 + 31) {
      const u16*  Kb = &KshF[cur * 8192];
      const char* Vb = (const char*)&VshF[cur * 8192];

      // ---- QK^T swapped: sf[qg][nb][jj] = S[kv=kv0+nb*16+g*4+jj][q=q0+w*32+qg*16+c]
      f32x4 sf[2][4];
#pragma unroll
      for (int qg = 0; qg < 2; ++qg)
#pragma unroll
        for (int nb = 0; nb < 4; ++nb) sf[qg][nb] = z4;

      __builtin_amdgcn_s_setprio(1);
#pragma unroll
      for (int kc = 0; kc < 4; ++kc) {
#pragma unroll
        for (int nb = 0; nb < 4; ++nb) {
          const int r = nb * 16 + c;
          const int s2 = (kc * 4 + g) ^ (c & 7);          // r&7 == c&7
          const bf16x8 kf = *(const bf16x8*)&Kb[r * 128 + s2 * 8];
          sf[0][nb] = __builtin_amdgcn_mfma_f32_16x16x32_bf16(kf, qf[0][kc], sf[0][nb], 0, 0, 0);
          sf[1][nb] = __builtin_amdgcn_mfma_f32_16x16x32_bf16(kf, qf[1][kc], sf[1][nb], 0, 0, 0);
        }
      }
      __builtin_amdgcn_s_setprio(0);

      // ---- online softmax (lane owns q-col); defer-max skips rescale
#pragma unroll
      for (int qg = 0; qg < 2; ++qg) {
        const int qcol = q0 + w * 32 + qg * 16 + c;
        const bool doMask = (kv0 + 63 > q0 + w * 32 + qg * 16);
        float mx = -3e38f;
#pragma unroll
        for (int nb = 0; nb < 4; ++nb)
#pragma unroll
          for (int jj = 0; jj < 4; ++jj) {
            float sv = sf[qg][nb][jj];
            if (doMask) {
              const int kk = kv0 + nb * 16 + g * 4 + jj;
              sv = (kk > qcol) ? -3e38f : sv;
              sf[qg][nb][jj] = sv;
            }
            mx = fmaxf(mx, sv);
          }
        mx = fmaxf(mx, __shfl_xor(mx, 16));
        mx = fmaxf(mx, __shfl_xor(mx, 32));

        if (__all(mx <= m_i[qg] + THRS_)) {
          // defer: keep old max, no O/l rescale (P bounded by 2^8)
          const float mk = m_i[qg] * K1_;
          float rs = 0.f;
#pragma unroll
          for (int nb = 0; nb < 4; ++nb)
#pragma unroll
            for (int jj = 0; jj < 4; ++jj) {
              const float p = exp2f(fmaf(sf[qg][nb][jj], K1_, -mk));
              sf[qg][nb][jj] = p;
              rs += p;
            }
          rs += __shfl_xor(rs, 16);
          rs += __shfl_xor(rs, 32);
          l_i[qg] += rs;
        } else {
          const float mnew = fmaxf(m_i[qg], mx);
          const float fsc = exp2f((m_i[qg] - mnew) * K1_);
          m_i[qg] = mnew;
          const float mk = mnew * K1_;
          float rs = 0.f;
#pragma unroll
          for (int nb = 0; nb < 4; ++nb)
#pragma unroll
            for (int jj = 0; jj < 4; ++jj) {
              const float p = exp2f(fmaf(sf[qg][nb][jj], K1_, -mk));
              sf[qg][nb][jj] = p;
              rs += p;
            }
          rs += __shfl_xor(rs, 16);
          rs += __shfl_xor(rs, 32);
          l_i[qg] = l_i[qg] * fsc + rs;
          float fq[4];
#pragma unroll
          for (int j = 0; j < 4; ++j) fq[j] = __shfl(fsc, g * 4 + j);
#pragma unroll
          for (int nb = 0; nb < 8; ++nb)
#pragma unroll
            for (int j = 0; j < 4; ++j) oacc[qg][nb][j] *= fq[j];
        }
      }

      // ---- pack P into PV A-frags: kappa=g*8+e -> kv = kc2*32 + (e>>2)*16 + g*4 + (e&3)
      bf16x8 paq0, paq1, pbq0, pbq1;
#pragma unroll
      for (int jj = 0; jj < 4; ++jj) {
        paq0[jj] = (__bf16)sf[0][0][jj]; paq0[4 + jj] = (__bf16)sf[0][1][jj];
        pbq0[jj] = (__bf16)sf[0][2][jj]; pbq0[4 + jj] = (__bf16)sf[0][3][jj];
        paq1[jj] = (__bf16)sf[1][0][jj]; paq1[4 + jj] = (__bf16)sf[1][1][jj];
        pbq1[jj] = (__bf16)sf[1][2][jj]; pbq1[4 + jj] = (__bf16)sf[1][3][jj];
      }

      // ---- PV: B-frag = V[kv(kappa)][d=nb*16+c] via two ds_read_b64 (XOR-swizzled)
      __builtin_amdgcn_s_setprio(1);
#pragma unroll
      for (int kc2 = 0; kc2 < 2; ++kc2) {
        const bf16x8 pa0 = kc2 ? pbq0 : paq0;
        const bf16x8 pa1 = kc2 ? pbq1 : paq1;
        const uint32_t vk = voff ^ (uint32_t)(kc2 << 6);
#pragma unroll
        for (int nb = 0; nb < 8; ++nb) {
          union { intx2 h[2]; bf16x8 v; } u_;
          u_.h[0] = *(const intx2*)(Vb + (vk + nb * 2048));          // kv low 16 (j=0..3)
          u_.h[1] = *(const intx2*)(Vb + ((vk ^ 32u) + nb * 2048));  // kv high 16 (j=4..7)
          oacc[0][nb] = __builtin_amdgcn_mfma_f32_16x16x32_bf16(pa0, u_.v, oacc[0][nb], 0, 0, 0);
          oacc[1][nb] = __builtin_amdgcn_mfma_f32_16x16x32_bf16(pa1, u_.v, oacc[1][nb], 0, 0, 0);
        }
      }
      __builtin_amdgcn_s_setprio(0);
    }

    __syncthreads();   // drains vmcnt (next tile staged) + all reads of cur done
  }

  // epilogue: normalize, write O as (b, s, h*128+d) bf16
#pragma unroll
  for (int qg = 0; qg < 2; ++qg)
#pragma unroll
    for (int j = 0; j < 4; ++j) {
      const float li = __shfl(l_i[qg], g * 4 + j);
      const float inv = 1.f / li;
      const int srow = q0 + w * 32 + qg * 16 + g * 4 + j;
      u16* op = O + ((size_t)(b * S_ + srow)) * HID_ + (bh & 15) * D_ + c;
#pragma unroll
      for (int nb = 0; nb < 8; ++nb) op[nb * 16] = f2bf(oacc[qg][nb][j] * inv);
    }
}

// ---------------- host launch ----------------
extern "C" void kernel_launch(void* const* d_in, const int* in_sizes, int n_in,
                              void* d_out, int out_size, void* d_ws, size_t ws_size,
                              hipStream_t stream) {
  const float* x    = (const float*)d_in[0];
  const float* cosb = (const float*)d_in[1];
  const float* sinb = (const float*)d_in[2];
  const float* Wq   = (const float*)d_in[3];
  const float* Wk   = (const float*)d_in[4];
  const float* Wv   = (const float*)d_in[5];
  const float* Wo   = (const float*)d_in[6];
  float* out = (float*)d_out;

  u16*   xb   = (u16*)d_ws;                                // 4096*2048
  u16*   Wt   = xb  + (size_t)4096 * 2048;                 // 3072*2048
  u16*   Wot  = Wt  + (size_t)3072 * 2048;                 // 2048*2048
  u16*   qkv  = Wot + (size_t)2048 * 2048;                 // 4096*3072 bf16
  u16*   Qr   = qkv + (size_t)4096 * 3072;                 // (B,H,S,D)
  u16*   Kr   = Qr  + (size_t)B_ * H_ * S_ * D_;           // (B,HKV,S,D)
  u16*   Vtb  = Kr  + (size_t)B_ * HKV_ * S_ * D_;         // (B,HKV,D,S) transposed
  u16*   Ob   = Vtb + (size_t)B_ * HKV_ * S_ * D_;         // (B,S,HID)

  cast_f32_bf16<<<8192, 256, 0, stream>>>(x, xb, (B_ * S_ * HID_) / 4);

  dim3 tb(32, 8);
  transpose_cast_all<<<dim3(10240), tb, 0, stream>>>(Wq, Wk, Wv, Wo, Wt, Wot);

  // QKV projection (bf16 out), 1-D grid with XCD-chunked swizzle; gx = M/128 = 32
  gemm_bt<1><<<dim3(768), 256, 0, stream>>>(xb, Wt, qkv, 4096, 3072, 2048, 32);

  rope_scatter<<<20480, 256, 0, stream>>>(qkv, cosb, sinb, Qr, Kr);
  v_transpose<<<dim3(4, 64, 8), tb, 0, stream>>>(qkv, Vtb);

  attn_kernel<<<dim3(512), 256, 0, stream>>>(Qr, Kr, Vtb, Ob);

  // output projection (f32 out)
  gemm_bt<0><<<dim3(512), 256, 0, stream>>>(Ob, Wot, out, 4096, 2048, 2048, 32);
}